// Round 6
// baseline (93.197 us; speedup 1.0000x reference)
//
#include <hip/hip_runtime.h>

// TripletLoss, N=384, D=512, fp32 in, int labels, fp32 scalar out.
// loss = sum_a sum_p sum_n relu(d(a,p)-d(a,n)+1) / num_valid (diag counts as pos)
//
// R12 post-mortem: 3x traffic cut -> ZERO gain (kernel ~39 vs ~37us). Three
// structurally different kernels all pin at ~40us with all pipes idle. New
// theory: the 268MB workspace poison right before us dirties the entire 256MB
// L3 (evicting X); its HBM writeback drain overlaps our kernel, so every cold
// X miss sees multi-us latency. Kernel FETCH 3.1MB over 43us = 72 GB/s ->
// MLP-starved (prior kernels held only ~8 loads in flight, VGPR=68).
//
// R13: same proven dataflow as R10 (384 blocks x 1 anchor, 6 waves, row-per-
// wave-iteration coalesced loads, 3-level shfl_xor to 8-lane coset partials,
// proven ballot-compaction phase 2) but with explicit deep software pipeline:
// two 8-row register batches (P/Q = 32 float4 in flight, issued 2 batches
// ahead of use, fully unrolled -> static reg indexing). The first 32 cold
// misses issue before ANY other work. Anchor fragments read directly from
// global (same addresses as row-a sweep loads -> bitwise-identical -> diag
// dv=0 exactly; also kills the s_xa staging barrier). R12's per-block row
// rotation kept to decorrelate the 384 address streams.

#define NPTS 384
#define DIM  512
#define NT   384
#define NW   (NT / 64)        // 6 waves

__global__ __launch_bounds__(NT) void triplet_fused(
    const float* __restrict__ X,
    const int*   __restrict__ labels,
    float*       __restrict__ out)
{
    __shared__ float s_part[NPTS * 8];            // 12 KB: 8 coset partials/row
    __shared__ float s_dp[NPTS];
    __shared__ float s_dn[NPTS];
    __shared__ int   s_lab[NPTS] __attribute__((aligned(16)));
    __shared__ int   s_cp[NW], s_cn[NW];
    __shared__ float s_red[NW];
    __shared__ int   s_nv[NW];

    const int t    = threadIdx.x;
    const int a    = blockIdx.x;
    const int lane = t & 63, w = t >> 6;

    const float4* X4 = (const float4*)X;          // row pitch 128 float4

    const int rot   = (a * 67) % NPTS;            // 67 coprime to 384
    const int rbase = w * 64;
    auto rowj = [&](int r) {                      // r in [0,64): global row idx
        int jj = rbase + r + rot;                 // < 768
        return (jj >= NPTS) ? jj - NPTS : jj;
    };

    // two 8-row register batches, fully unrolled -> static indices, no scratch
    float4 P0[8], P1[8], Q0[8], Q1[8];

#define LDB(B, base_) { \
    _Pragma("unroll") \
    for (int i = 0; i < 8; ++i) { \
        const float4* rp = X4 + (size_t)rowj((base_) + i) * (DIM / 4); \
        B##0[i] = rp[lane]; \
        B##1[i] = rp[lane + 64]; \
    } }

#define CMPB(B, base_) { \
    _Pragma("unroll") \
    for (int i = 0; i < 8; ++i) { \
        const int jj = rowj((base_) + i); \
        const float4 b0 = B##0[i]; \
        const float4 b1 = B##1[i]; \
        float d, s; \
        d = av0.x - b0.x; s = d * d; \
        d = av0.y - b0.y; s = fmaf(d, d, s); \
        d = av0.z - b0.z; s = fmaf(d, d, s); \
        d = av0.w - b0.w; s = fmaf(d, d, s); \
        d = av1.x - b1.x; s = fmaf(d, d, s); \
        d = av1.y - b1.y; s = fmaf(d, d, s); \
        d = av1.z - b1.z; s = fmaf(d, d, s); \
        d = av1.w - b1.w; s = fmaf(d, d, s); \
        s += __shfl_xor(s,  8, 64); \
        s += __shfl_xor(s, 16, 64); \
        s += __shfl_xor(s, 32, 64); \
        if (lane < 8) s_part[jj * 8 + lane] = s; \
    } }

    // ---- issue the first 32 cold misses IMMEDIATELY ------------------------
    LDB(P, 0);
    LDB(Q, 8);

    // ---- cheap setup overlaps the in-flight loads --------------------------
    s_lab[t] = labels[t];
    const int lab_a = labels[a];
    const float4* Xa = X4 + (size_t)a * (DIM / 4);
    const float4 av0 = Xa[lane];                  // anchor k-slice, from L1/L2
    const float4 av1 = Xa[lane + 64];

    // ---- pipelined distance sweep: compute batch i, loads 2 batches ahead --
    CMPB(P, 0);   LDB(P, 16);
    CMPB(Q, 8);   LDB(Q, 24);
    CMPB(P, 16);  LDB(P, 32);
    CMPB(Q, 24);  LDB(Q, 40);
    CMPB(P, 32);  LDB(P, 48);
    CMPB(Q, 40);  LDB(Q, 56);
    CMPB(P, 48);
    CMPB(Q, 56);
    __syncthreads();                              // s_part + s_lab complete

    // ---- finish distance d(a, t) from the 8 coset partials -----------------
    // row a: loads hit identical addresses as av0/av1 -> diffs exactly 0 -> dv=0
    const float4 q0 = *(const float4*)&s_part[t * 8];
    const float4 q1 = *(const float4*)&s_part[t * 8 + 4];
    const float dv = sqrtf(((q0.x + q0.y) + (q0.z + q0.w)) +
                           ((q1.x + q1.y) + (q1.z + q1.w)));

    // ---- ballot compaction into positives / negatives (proven) -------------
    const bool isp = (s_lab[t] == lab_a);         // diag j==a counts as pos
    const unsigned long long m = __ballot(isp);
    if (lane == 0) { s_cp[w] = __popcll(m); s_cn[w] = 64 - __popcll(m); }
    __syncthreads();

    int basep = 0, basen = 0, np = 0, nn = 0;
#pragma unroll
    for (int i = 0; i < NW; ++i) {
        if (i < w) { basep += s_cp[i]; basen += s_cn[i]; }
        np += s_cp[i]; nn += s_cn[i];
    }
    const unsigned long long blw = (1ull << lane) - 1ull;   // lane<64, safe
    if (isp) s_dp[basep + __popcll(m  & blw)] = dv;
    else     s_dn[basen + __popcll(~m & blw)] = dv;
    __syncthreads();

    // ---- pair sum: thread t owns negative n = t ----------------------------
    const bool  va  = (t < nn);
    const float dna = va ? s_dn[t] : 0.f;
    float local = 0.f;
    for (int p = 0; p < np; ++p) {
        const float c = s_dp[p] + 1.0f;           // MARGIN
        if (va) local += fmaxf(c - dna, 0.f);
    }

    // ---- global num_valid from labels alone (identical in every block) -----
    // num_valid = sum_t np(t) * (384 - np(t)); np(t) = #{j: lab[j]==lab[t]}
    const int myl = s_lab[t];
    int npt = 0;
    const int4* L4 = (const int4*)s_lab;
#pragma unroll 8
    for (int j4 = 0; j4 < NPTS / 4; ++j4) {
        const int4 l = L4[j4];                    // broadcast read
        npt += (l.x == myl) + (l.y == myl) + (l.z == myl) + (l.w == myl);
    }
    int nvl = npt * (NPTS - npt);

    // ---- block reduce + atomic finish --------------------------------------
    for (int off = 32; off; off >>= 1) {
        local += __shfl_down(local, off, 64);
        nvl   += __shfl_down(nvl,   off, 64);
    }
    if (lane == 0) { s_red[w] = local; s_nv[w] = nvl; }
    __syncthreads();
    if (t == 0) {
        float bs = 0.f; int nv = 0;
#pragma unroll
        for (int i = 0; i < NW; ++i) { bs += s_red[i]; nv += s_nv[i]; }
        // out is memset to 0 by the harness before each launch
        atomicAdd(out, (float)((double)bs / ((double)nv + 1e-16)));
    }
#undef LDB
#undef CMPB
}

extern "C" void kernel_launch(void* const* d_in, const int* in_sizes, int n_in,
                              void* d_out, int out_size, void* d_ws, size_t ws_size,
                              hipStream_t stream) {
    (void)in_sizes; (void)n_in; (void)out_size; (void)d_ws; (void)ws_size;
    const float* X      = (const float*)d_in[0];
    const int*   labels = (const int*)d_in[1];
    triplet_fused<<<dim3(NPTS), dim3(NT), 0, stream>>>(X, labels, (float*)d_out);
}

// Round 7
// 79.611 us; speedup vs baseline: 1.1707x; 1.1707x over previous
//
#include <hip/hip_runtime.h>

// TripletLoss, N=384, D=512, fp32 in, int labels, fp32 scalar out.
// loss = sum_a sum_p sum_n relu(d(a,p)-d(a,n)+1) / num_valid (diag counts as pos)
//
// R13 post-mortem: deep-MLP fusion regressed (60us, compiler clamped VGPR=84
// and re-serialized). Assembling R8-R13: every fused structure has each of 384
// blocks re-reading all of X -> ~1.2MB of cache-line traffic per CU, and
// kernel time pins at ~40-60us regardless of coalescing/rotation/MLP/L2 cuts.
// R8 steady state: 37KB HBM fetch, still 53.7us -> the wall is per-CU L1-line
// throughput, not HBM/L3/aggregate-L2. Only tiling with reuse cuts it: the
// round-0 3-kernel tiled version (75.4us e2e) had ~0.1MB/CU in K1.
//
// R14: back to the tiled split, minus one kernel + one boundary.
//   K1 = round-0 dist_tile VERBATIM (144 blocks, 32x32 tile, 16x reuse).
//   K2 = round-0 pair_sums + R9-proven label-only global num_valid +
//        atomicAdd(out) finisher (each piece absmax-0.0-verified).
// Workspace holds only D (overwritten every iteration before it's read).

#define NPTS 384
#define DIM  512
#define TS   32          // C-tile 32x32
#define BK   64
#define PITCH 68         // BK+4 pad floats; 272B row pitch keeps float4 align
#define NT1  256
#define NT2  384
#define NW2  (NT2 / 64)  // 6 waves

// ---------------- K1: distance matrix (GEMM-shaped, diff^2 form) ------------
__global__ __launch_bounds__(NT1) void dist_tile(const float* __restrict__ X,
                                                 float* __restrict__ D) {
    __shared__ float As[TS * PITCH];
    __shared__ float Bs[TS * PITCH];
    const int t  = threadIdx.x;
    const int tx = t & 15, ty = t >> 4;        // 16x16 thread grid, 2x2 per thread
    const int bi = blockIdx.y * TS;
    const int bj = blockIdx.x * TS;

    const float4* X4 = (const float4*)X;       // row pitch DIM/4 = 128 float4
    const int r0 = t >> 4, c4 = t & 15;        // staging: 32 rows x 16 float4

    float4 pa0, pa1, pb0, pb1;                 // register prefetch
    int k4 = 0;
    {   // stage tile 0
        pa0 = X4[(size_t)(bi + r0)      * (DIM/4) + k4 + c4];
        pa1 = X4[(size_t)(bi + r0 + 16) * (DIM/4) + k4 + c4];
        pb0 = X4[(size_t)(bj + r0)      * (DIM/4) + k4 + c4];
        pb1 = X4[(size_t)(bj + r0 + 16) * (DIM/4) + k4 + c4];
        *(float4*)&As[ r0       * PITCH + c4*4] = pa0;
        *(float4*)&As[(r0 + 16) * PITCH + c4*4] = pa1;
        *(float4*)&Bs[ r0       * PITCH + c4*4] = pb0;
        *(float4*)&Bs[(r0 + 16) * PITCH + c4*4] = pb1;
    }
    __syncthreads();

    float acc00 = 0.f, acc01 = 0.f, acc10 = 0.f, acc11 = 0.f;

    for (int kt = 0; kt < DIM / BK; ++kt) {
        if (kt < DIM / BK - 1) {               // prefetch next K-tile into regs
            k4 = (kt + 1) * (BK / 4);
            pa0 = X4[(size_t)(bi + r0)      * (DIM/4) + k4 + c4];
            pa1 = X4[(size_t)(bi + r0 + 16) * (DIM/4) + k4 + c4];
            pb0 = X4[(size_t)(bj + r0)      * (DIM/4) + k4 + c4];
            pb1 = X4[(size_t)(bj + r0 + 16) * (DIM/4) + k4 + c4];
        }
#pragma unroll
        for (int kk = 0; kk < BK / 4; ++kk) {
            const float4 a0 = *(const float4*)&As[(2*ty)   * PITCH + kk*4];
            const float4 a1 = *(const float4*)&As[(2*ty+1) * PITCH + kk*4];
            const float4 b0 = *(const float4*)&Bs[(2*tx)   * PITCH + kk*4];
            const float4 b1 = *(const float4*)&Bs[(2*tx+1) * PITCH + kk*4];
            float d;
            d = a0.x - b0.x; acc00 = fmaf(d, d, acc00);
            d = a0.y - b0.y; acc00 = fmaf(d, d, acc00);
            d = a0.z - b0.z; acc00 = fmaf(d, d, acc00);
            d = a0.w - b0.w; acc00 = fmaf(d, d, acc00);
            d = a0.x - b1.x; acc01 = fmaf(d, d, acc01);
            d = a0.y - b1.y; acc01 = fmaf(d, d, acc01);
            d = a0.z - b1.z; acc01 = fmaf(d, d, acc01);
            d = a0.w - b1.w; acc01 = fmaf(d, d, acc01);
            d = a1.x - b0.x; acc10 = fmaf(d, d, acc10);
            d = a1.y - b0.y; acc10 = fmaf(d, d, acc10);
            d = a1.z - b0.z; acc10 = fmaf(d, d, acc10);
            d = a1.w - b0.w; acc10 = fmaf(d, d, acc10);
            d = a1.x - b1.x; acc11 = fmaf(d, d, acc11);
            d = a1.y - b1.y; acc11 = fmaf(d, d, acc11);
            d = a1.z - b1.z; acc11 = fmaf(d, d, acc11);
            d = a1.w - b1.w; acc11 = fmaf(d, d, acc11);
        }
        __syncthreads();
        if (kt < DIM / BK - 1) {
            *(float4*)&As[ r0       * PITCH + c4*4] = pa0;
            *(float4*)&As[(r0 + 16) * PITCH + c4*4] = pa1;
            *(float4*)&Bs[ r0       * PITCH + c4*4] = pb0;
            *(float4*)&Bs[(r0 + 16) * PITCH + c4*4] = pb1;
            __syncthreads();
        }
    }

    // diagonal tiles load identical As/Bs rows -> i==j diffs exactly 0 -> d=0
    const int gi = bi + 2*ty, gj = bj + 2*tx;
    *(float2*)&D[(size_t)gi      * NPTS + gj] = make_float2(sqrtf(acc00), sqrtf(acc01));
    *(float2*)&D[(size_t)(gi+1)  * NPTS + gj] = make_float2(sqrtf(acc10), sqrtf(acc11));
}

// ---------------- K2: compaction + pair sum + global finish -----------------
__global__ __launch_bounds__(NT2) void pair_reduce(const float* __restrict__ D,
                                                   const int* __restrict__ labels,
                                                   float* __restrict__ out) {
    __shared__ float s_dp[NPTS];
    __shared__ float s_dn[NPTS];
    __shared__ int   s_lab[NPTS] __attribute__((aligned(16)));
    __shared__ int   s_cp[NW2], s_cn[NW2];
    __shared__ float s_red[NW2];
    __shared__ int   s_nv[NW2];

    const int t = threadIdx.x, lane = t & 63, w = t >> 6;
    const int a = blockIdx.x;

    const float dv = D[(size_t)a * NPTS + t];
    s_lab[t] = labels[t];
    const int lab_a = labels[a];
    __syncthreads();

    // ---- ballot compaction into positives / negatives (proven) -------------
    const bool isp = (s_lab[t] == lab_a);         // diag j==a counts as pos
    const unsigned long long m = __ballot(isp);
    if (lane == 0) { s_cp[w] = __popcll(m); s_cn[w] = 64 - __popcll(m); }
    __syncthreads();

    int basep = 0, basen = 0, np = 0, nn = 0;
#pragma unroll
    for (int i = 0; i < NW2; ++i) {
        if (i < w) { basep += s_cp[i]; basen += s_cn[i]; }
        np += s_cp[i]; nn += s_cn[i];
    }
    const unsigned long long blw = (1ull << lane) - 1ull;   // lane<64, safe
    if (isp) s_dp[basep + __popcll(m  & blw)] = dv;
    else     s_dn[basen + __popcll(~m & blw)] = dv;
    __syncthreads();

    // ---- pair sum: thread t owns negative n = t ----------------------------
    const bool  va  = (t < nn);
    const float dna = va ? s_dn[t] : 0.f;
    float local = 0.f;
    for (int p = 0; p < np; ++p) {
        const float c = s_dp[p] + 1.0f;           // MARGIN
        if (va) local += fmaxf(c - dna, 0.f);
    }

    // ---- global num_valid from labels alone (identical in every block) -----
    // num_valid = sum_t np(t) * (384 - np(t)); np(t) = #{j: lab[j]==lab[t]}
    const int myl = s_lab[t];
    int npt = 0;
    const int4* L4 = (const int4*)s_lab;
#pragma unroll 8
    for (int j4 = 0; j4 < NPTS / 4; ++j4) {
        const int4 l = L4[j4];                    // broadcast read
        npt += (l.x == myl) + (l.y == myl) + (l.z == myl) + (l.w == myl);
    }
    int nvl = npt * (NPTS - npt);

    // ---- block reduce + atomic finish --------------------------------------
    for (int off = 32; off; off >>= 1) {
        local += __shfl_down(local, off, 64);
        nvl   += __shfl_down(nvl,   off, 64);
    }
    if (lane == 0) { s_red[w] = local; s_nv[w] = nvl; }
    __syncthreads();
    if (t == 0) {
        float bs = 0.f; int nv = 0;
#pragma unroll
        for (int i = 0; i < NW2; ++i) { bs += s_red[i]; nv += s_nv[i]; }
        // out is memset to 0 by the harness before each verified launch
        atomicAdd(out, (float)((double)bs / ((double)nv + 1e-16)));
    }
}

extern "C" void kernel_launch(void* const* d_in, const int* in_sizes, int n_in,
                              void* d_out, int out_size, void* d_ws, size_t ws_size,
                              hipStream_t stream) {
    (void)in_sizes; (void)n_in; (void)out_size; (void)ws_size;
    const float* X      = (const float*)d_in[0];
    const int*   labels = (const int*)d_in[1];

    float* Dmat = (float*)d_ws;                   // 589824 B, rewritten each run

    dist_tile  <<<dim3(NPTS / TS, NPTS / TS), dim3(NT1), 0, stream>>>(X, Dmat);
    pair_reduce<<<dim3(NPTS),                 dim3(NT2), 0, stream>>>(Dmat, labels,
                                                                     (float*)d_out);
}